// Round 2
// baseline (539.385 us; speedup 1.0000x reference)
//
#include <hip/hip_runtime.h>
#include <hip/hip_bf16.h>

#define N_IN 128
#define N_OUT 64

// ---------------- degree count ----------------
__global__ void deg_kernel(const int* __restrict__ src, float* __restrict__ deg, int nE) {
    int i = blockIdx.x * blockDim.x + threadIdx.x;
    int stride = gridDim.x * blockDim.x;
    for (; i < nE; i += stride) {
        atomicAdd(&deg[src[i]], 1.0f);
    }
}

// ---------------- norm = rsqrt(max(deg,1)) (in place) ----------------
__global__ void norm_kernel(float* __restrict__ deg, int nN) {
    int i = blockIdx.x * blockDim.x + threadIdx.x;
    if (i < nN) deg[i] = rsqrtf(fmaxf(deg[i], 1.0f));
}

// ---------------- h = bf16( (feat @ W) * norm[:,None] ) ----------------
// block = 512 threads = 8 nodes x 64 cols. W staged in LDS (32KB), 8 feat rows in LDS (4KB).
__global__ __launch_bounds__(512) void gemm_kernel(const float* __restrict__ feat,
                                                   const float* __restrict__ w,
                                                   const float* __restrict__ nrm,
                                                   __hip_bfloat16* __restrict__ h, int nN) {
    __shared__ float wl[N_IN][N_OUT];   // 32 KB
    __shared__ float fl[8][N_IN];       // 4 KB
    int t = threadIdx.x;
    for (int i = t; i < N_IN * N_OUT; i += 512) {
        ((float*)wl)[i] = w[i];
    }
    int nodeBase = blockIdx.x * 8;
    for (int i = t; i < 8 * N_IN; i += 512) {
        int node = nodeBase + i / N_IN;
        ((float*)fl)[i] = (node < nN) ? feat[(size_t)node * N_IN + (i & (N_IN - 1))] : 0.0f;
    }
    __syncthreads();

    int g = t >> 6;        // node group 0..7
    int col = t & 63;      // output column
    int node = nodeBase + g;
    if (node >= nN) return;

    float acc = 0.0f;
#pragma unroll
    for (int k = 0; k < N_IN; ++k) {
        acc += fl[g][k] * wl[k][col];
    }
    h[(size_t)node * N_OUT + col] = __float2bfloat16(acc * nrm[node]);
}

// ---------------- scatter: out[dst] += h[src], one wave per edge ----------------
__global__ void scatter_kernel(const int* __restrict__ src, const int* __restrict__ dst,
                               const __hip_bfloat16* __restrict__ h, float* __restrict__ out,
                               int nE) {
    int lane = threadIdx.x & 63;
    int wid  = (blockIdx.x * blockDim.x + threadIdx.x) >> 6;
    int nW   = (gridDim.x * blockDim.x) >> 6;
    for (int e = wid; e < nE; e += nW) {
        int s = src[e];   // broadcast load
        int d = dst[e];
        float v = __bfloat162float(h[(size_t)s * N_OUT + lane]);  // coalesced 128B gather
        atomicAdd(&out[(size_t)d * N_OUT + lane], v);             // coalesced 64-lane atomic
    }
}

// ---------------- out = out * norm[:,None] + bias, float4 ----------------
__global__ void finalize_kernel(float* __restrict__ out, const float* __restrict__ nrm,
                                const float* __restrict__ bias, int nN) {
    int i = blockIdx.x * blockDim.x + threadIdx.x;    // one float4 each
    int total = nN * (N_OUT / 4);
    if (i >= total) return;
    float4 v = ((float4*)out)[i];
    int node = i >> 4;                                // 16 float4 per node row
    float nn = nrm[node];
    float4 b = ((const float4*)bias)[i & 15];
    v.x = v.x * nn + b.x;
    v.y = v.y * nn + b.y;
    v.z = v.z * nn + b.z;
    v.w = v.w * nn + b.w;
    ((float4*)out)[i] = v;
}

extern "C" void kernel_launch(void* const* d_in, const int* in_sizes, int n_in,
                              void* d_out, int out_size, void* d_ws, size_t ws_size,
                              hipStream_t stream) {
    const float* feat = (const float*)d_in[0];
    const float* w    = (const float*)d_in[1];
    const float* bias = (const float*)d_in[2];
    const int*   src  = (const int*)d_in[3];
    const int*   dst  = (const int*)d_in[4];
    float* out = (float*)d_out;

    int nN = in_sizes[0] / N_IN;      // 100000
    int nE = in_sizes[3];             // 1600000

    // workspace layout: [deg/norm: nN floats][h: nN*64 bf16]  => ~13.2 MB total
    float* deg = (float*)d_ws;
    size_t degBytes = (((size_t)nN * sizeof(float)) + 511) & ~(size_t)511;
    __hip_bfloat16* h = (__hip_bfloat16*)((char*)d_ws + degBytes);

    hipMemsetAsync(deg, 0, (size_t)nN * sizeof(float), stream);
    hipMemsetAsync(out, 0, (size_t)out_size * sizeof(float), stream);

    deg_kernel<<<1024, 256, 0, stream>>>(src, deg, nE);
    norm_kernel<<<(nN + 255) / 256, 256, 0, stream>>>(deg, nN);
    gemm_kernel<<<(nN + 7) / 8, 512, 0, stream>>>(feat, w, deg, h, nN);
    scatter_kernel<<<4096, 256, 0, stream>>>(src, dst, h, out, nE);
    finalize_kernel<<<(nN * (N_OUT / 4) + 255) / 256, 256, 0, stream>>>(out, deg, bias, nN);
}

// Round 3
// 453.317 us; speedup vs baseline: 1.1899x; 1.1899x over previous
//
#include <hip/hip_runtime.h>
#include <hip/hip_bf16.h>

#define N_IN 128
#define N_OUT 64

// ---------------- count out-degree (src) and in-degree (dst) ----------------
__global__ void count_kernel(const int* __restrict__ src, const int* __restrict__ dst,
                             int* __restrict__ degS, int* __restrict__ degD, int nE) {
    int i = blockIdx.x * blockDim.x + threadIdx.x;
    int stride = gridDim.x * blockDim.x;
    for (; i < nE; i += stride) {
        atomicAdd(&degS[src[i]], 1);
        atomicAdd(&degD[dst[i]], 1);
    }
}

// ---------------- norm = rsqrt(max(degS,1)), written in place over degS ----------------
__global__ void norm_kernel(int* __restrict__ degS, float* __restrict__ nrm, int nN) {
    int i = blockIdx.x * blockDim.x + threadIdx.x;
    if (i < nN) {
        float d = (float)degS[i];
        nrm[i] = rsqrtf(fmaxf(d, 1.0f));
    }
}

// ---------------- exclusive scan of degD -> base (3 kernels, 2048 elems/block) ----------------
__global__ void scan1_kernel(const int* __restrict__ degD, int* __restrict__ base,
                             int* __restrict__ partial, int nN) {
    __shared__ int sh[256];
    int b = blockIdx.x, t = threadIdx.x;
    int g0 = b * 2048 + t * 8;
    int v[8];
    int s = 0;
#pragma unroll
    for (int i = 0; i < 8; ++i) {
        int idx = g0 + i;
        v[i] = (idx < nN) ? degD[idx] : 0;
        s += v[i];
    }
    sh[t] = s;
    __syncthreads();
    for (int o = 1; o < 256; o <<= 1) {
        int x = (t >= o) ? sh[t - o] : 0;
        __syncthreads();
        sh[t] += x;
        __syncthreads();
    }
    int run = (t == 0) ? 0 : sh[t - 1];
    if (t == 255) partial[b] = sh[255];
#pragma unroll
    for (int i = 0; i < 8; ++i) {
        int idx = g0 + i;
        if (idx < nN) base[idx] = run;
        run += v[i];
    }
}

__global__ void scan2_kernel(int* __restrict__ partial, int nb) {
    __shared__ int sh[256];
    int t = threadIdx.x;
    sh[t] = (t < nb) ? partial[t] : 0;
    __syncthreads();
    for (int o = 1; o < 256; o <<= 1) {
        int x = (t >= o) ? sh[t - o] : 0;
        __syncthreads();
        sh[t] += x;
        __syncthreads();
    }
    if (t < nb) partial[t] = (t == 0) ? 0 : sh[t - 1];
}

__global__ void scan3_kernel(int* __restrict__ base, const int* __restrict__ partial, int nN) {
    int i = blockIdx.x * blockDim.x + threadIdx.x;
    if (i < nN) base[i] += partial[i >> 11];
}

// ---------------- CSR fill: base used as cursor; after this base[n] = end_n ----------------
__global__ void fill_kernel(const int* __restrict__ src, const int* __restrict__ dst,
                            int* __restrict__ base, int* __restrict__ csr, int nE) {
    int i = blockIdx.x * blockDim.x + threadIdx.x;
    int stride = gridDim.x * blockDim.x;
    for (; i < nE; i += stride) {
        int pos = atomicAdd(&base[dst[i]], 1);
        csr[pos] = src[i];
    }
}

// ---------------- h = bf16( (feat @ W) * norm[:,None] )  (ws-rich path) ----------------
__global__ __launch_bounds__(512) void gemm_kernel(const float* __restrict__ feat,
                                                   const float* __restrict__ w,
                                                   const float* __restrict__ nrm,
                                                   __hip_bfloat16* __restrict__ h, int nN) {
    __shared__ float wl[N_IN][N_OUT];   // 32 KB
    __shared__ float fl[8][N_IN];       // 4 KB
    int t = threadIdx.x;
    for (int i = t; i < N_IN * N_OUT; i += 512) ((float*)wl)[i] = w[i];
    int nodeBase = blockIdx.x * 8;
    for (int i = t; i < 8 * N_IN; i += 512) {
        int node = nodeBase + i / N_IN;
        ((float*)fl)[i] = (node < nN) ? feat[(size_t)node * N_IN + (i & (N_IN - 1))] : 0.0f;
    }
    __syncthreads();

    int g = t >> 6, col = t & 63;
    int node = nodeBase + g;
    if (node >= nN) return;

    float acc = 0.0f;
#pragma unroll
    for (int k = 0; k < N_IN; ++k) acc += fl[g][k] * wl[k][col];
    h[(size_t)node * N_OUT + col] = __float2bfloat16(acc * nrm[node]);
}

// ---------------- atomic-free aggregate from h: one wave per dst node ----------------
__global__ __launch_bounds__(256) void gatherH_kernel(const int* __restrict__ csr,
                                                      const int* __restrict__ endArr,
                                                      const int* __restrict__ degD,
                                                      const __hip_bfloat16* __restrict__ h,
                                                      const float* __restrict__ nrm,
                                                      const float* __restrict__ bias,
                                                      float* __restrict__ out, int nN) {
    int lane = threadIdx.x & 63;
    int n = (blockIdx.x * blockDim.x + threadIdx.x) >> 6;
    if (n >= nN) return;
    int end = endArr[n];
    int start = end - degD[n];
    float acc = 0.0f;
    int e = start;
    for (; e + 1 < end; e += 2) {           // 2x unroll: two independent gathers in flight
        int s0 = csr[e], s1 = csr[e + 1];
        float v0 = __bfloat162float(h[(size_t)s0 * N_OUT + lane]);
        float v1 = __bfloat162float(h[(size_t)s1 * N_OUT + lane]);
        acc += v0;
        acc += v1;
    }
    if (e < end) acc += __bfloat162float(h[(size_t)csr[e] * N_OUT + lane]);
    out[(size_t)n * N_OUT + lane] = acc * nrm[n] + bias[lane];
}

// ---------------- fused path (small ws): gather feat rows, mini-GEMM per node ----------------
__global__ __launch_bounds__(256) void fusedF_kernel(const int* __restrict__ csr,
                                                     const int* __restrict__ endArr,
                                                     const int* __restrict__ degD,
                                                     const float* __restrict__ feat,
                                                     const float* __restrict__ w,
                                                     const float* __restrict__ nrm,
                                                     const float* __restrict__ bias,
                                                     float* __restrict__ out, int nN) {
    __shared__ float wl[N_IN][N_OUT];   // 32 KB
    __shared__ float sacc[4][N_IN];     // 2 KB
    int t = threadIdx.x;
    for (int i = t; i < N_IN * N_OUT; i += 256) ((float*)wl)[i] = w[i];
    __syncthreads();

    int lane = t & 63, wv = t >> 6;
    int n = blockIdx.x * 4 + wv;
    if (n >= nN) return;

    int end = endArr[n];
    int start = end - degD[n];
    float ax = 0.0f, ay = 0.0f;                  // feat dims 2*lane, 2*lane+1
    for (int e = start; e < end; ++e) {
        int s = csr[e];
        float nw = nrm[s];
        float2 f = ((const float2*)feat)[(size_t)s * (N_IN / 2) + lane];
        ax += nw * f.x;
        ay += nw * f.y;
    }
    // wave-private LDS staging (no barrier needed: same-wave ds_write -> ds_read)
    sacc[wv][2 * lane]     = ax;
    sacc[wv][2 * lane + 1] = ay;
    float acc = 0.0f;
#pragma unroll
    for (int k = 0; k < N_IN; ++k) acc += sacc[wv][k] * wl[k][lane];
    out[(size_t)n * N_OUT + lane] = acc * nrm[n] + bias[lane];
}

extern "C" void kernel_launch(void* const* d_in, const int* in_sizes, int n_in,
                              void* d_out, int out_size, void* d_ws, size_t ws_size,
                              hipStream_t stream) {
    const float* feat = (const float*)d_in[0];
    const float* w    = (const float*)d_in[1];
    const float* bias = (const float*)d_in[2];
    const int*   src  = (const int*)d_in[3];
    const int*   dst  = (const int*)d_in[4];
    float* out = (float*)d_out;

    int nN = in_sizes[0] / N_IN;      // 100000
    int nE = in_sizes[3];             // 1600000

    // ---- workspace layout ----
    size_t o = 0;
    auto alloc = [&](size_t bytes) { size_t r = o; o = (o + bytes + 1023) & ~(size_t)1023; return r; };
    char* wsc = (char*)d_ws;
    int*   degS    = (int*)(wsc + alloc((size_t)nN * 4));   // reused as norm (float) in place
    int*   degD    = (int*)(wsc + alloc((size_t)nN * 4));
    int*   base    = (int*)(wsc + alloc((size_t)nN * 4));
    int*   partial = (int*)(wsc + alloc(1024));
    int*   csr     = (int*)(wsc + alloc((size_t)nE * 4));
    size_t commonEnd = o;
    __hip_bfloat16* h = (__hip_bfloat16*)(wsc + alloc((size_t)nN * N_OUT * 2));
    bool useH = (ws_size >= o + 65536);            // h path fits with slack
    (void)commonEnd;
    float* nrm = (float*)degS;

    hipMemsetAsync(degS, 0, (size_t)nN * 4, stream);
    hipMemsetAsync(degD, 0, (size_t)nN * 4, stream);

    count_kernel<<<1024, 256, 0, stream>>>(src, dst, degS, degD, nE);
    norm_kernel<<<(nN + 255) / 256, 256, 0, stream>>>(degS, nrm, nN);

    int nb = (nN + 2047) / 2048;                   // 49 blocks, fits partial[256]
    scan1_kernel<<<nb, 256, 0, stream>>>(degD, base, partial, nN);
    scan2_kernel<<<1, 256, 0, stream>>>(partial, nb);
    scan3_kernel<<<(nN + 255) / 256, 256, 0, stream>>>(base, partial, nN);
    fill_kernel<<<1024, 256, 0, stream>>>(src, dst, base, csr, nE);   // base[n] -> end_n

    if (useH) {
        gemm_kernel<<<(nN + 7) / 8, 512, 0, stream>>>(feat, w, nrm, h, nN);
        gatherH_kernel<<<((nN * 64) + 255) / 256, 256, 0, stream>>>(csr, base, degD, h, nrm,
                                                                    bias, out, nN);
    } else {
        fusedF_kernel<<<(nN + 3) / 4, 256, 0, stream>>>(csr, base, degD, feat, w, nrm,
                                                        bias, out, nN);
    }
}